// Round 1
// 618.698 us; speedup vs baseline: 1.0481x; 1.0481x over previous
//
#include <hip/hip_runtime.h>
#include <float.h>

#define Nn 32
#define Ll 2048
#define Cc 128
#define NTILES 32
#define TILE 64                 // Ll / NTILES
#define OUTC 1172               // 3*384 + 20
#define NLC (Nn * Ll * Cc)      // 8388608
#define OUT_ELEMS ((size_t)Nn * Ll * OUTC)  // 76808192
#define NUNITS (3 * Nn * NTILES)            // 3072 half-wave units
#define AGG (NUNITS * Cc)                   // 393216 floats per array

typedef float  f4 __attribute__((ext_vector_type(4)));
typedef int    i4 __attribute__((ext_vector_type(4)));

__device__ __forceinline__ void nts4(f4* p, f4 v) { __builtin_nontemporal_store(v, p); }
__device__ __forceinline__ void nts1(float* p, float v) { __builtin_nontemporal_store(v, p); }

// ---------------- Phase 1: per-tile aggregates (float4 lanes) + MLP ----------------
// Last block (blockIdx == NUNITS/8) runs the tiny demographics MLP; all other
// blocks compute 8 half-wave tile units each. Aggregate stores stay cached
// (regular stores) -- they are re-read by k_apply's carry pass.
__global__ __launch_bounds__(256) void k_agg(
        const float* __restrict__ x0, const float* __restrict__ x1,
        const float* __restrict__ x2,
        f4* __restrict__ aggMax, i4* __restrict__ aggIdx, f4* __restrict__ aggSum,
        const float* __restrict__ dem, const float* __restrict__ W1,
        const float* __restrict__ b1, const float* __restrict__ W2,
        const float* __restrict__ b2, float* __restrict__ dvals) {
    if (blockIdx.x == NUNITS / 8) {
        int n = threadIdx.x;
        if (n >= Nn) return;
        float de[8], h[40];
#pragma unroll
        for (int k = 0; k < 8; ++k) de[k] = dem[n * 8 + k];
#pragma unroll
        for (int j = 0; j < 40; ++j) {
            float s = b1[j];
#pragma unroll
            for (int k = 0; k < 8; ++k) s += de[k] * W1[k * 40 + j];
            h[j] = fmaxf(s, 0.f);
        }
#pragma unroll
        for (int o = 0; o < 20; ++o) {
            float s = b2[o];
#pragma unroll
            for (int j = 0; j < 40; ++j) s += h[j] * W2[j * 20 + o];
            dvals[n * 20 + o] = fmaxf(s, 0.f);
        }
        return;
    }

    int unit = blockIdx.x * 8 + (threadIdx.x >> 5);   // (inp, n, tile)
    int lane = threadIdx.x & 31;                      // channels lane*4..lane*4+3
    int inp = unit >> 10;                             // / (Nn*NTILES)=1024
    int rem = unit & 1023;
    int n = rem >> 5;                                 // / NTILES
    int tile = rem & 31;
    const float* x = (inp == 0) ? x0 : ((inp == 1) ? x1 : x2);
    int t0 = tile * TILE;
    const f4* p = (const f4*)(x + ((size_t)n * Ll + t0) * Cc) + lane;

    f4 m = { -FLT_MAX, -FLT_MAX, -FLT_MAX, -FLT_MAX };
    i4 mi = { 0, 0, 0, 0 };
    f4 s = { 0.f, 0.f, 0.f, 0.f };
#pragma unroll 8
    for (int tl = 0; tl < TILE; ++tl) {
        f4 v = p[(size_t)tl * (Cc / 4)];
        int t = t0 + tl;
#pragma unroll
        for (int j = 0; j < 4; ++j) {
            s[j] += v[j];
            if (v[j] > m[j]) { m[j] = v[j]; mi[j] = t; }   // strict >: earlier wins ties
        }
    }
    int o = unit * (Cc / 4) + lane;
    aggMax[o] = m; aggIdx[o] = mi; aggSum[o] = s;
}

// ---- Phase 2 (fused into apply): per-unit redundant carry + rescan + writes ----
// Each half-wave unit combines the <=31 predecessor tile aggregates of its row
// (L2/L3-resident, ~71 MB total, loads independent of the combine chain), then
// streams its 64 timesteps and writes all outputs with nontemporal float4 stores.
__global__ __launch_bounds__(256) void k_apply(
        const float* __restrict__ x0, const float* __restrict__ x1,
        const float* __restrict__ x2,
        const f4* __restrict__ aggMax, const i4* __restrict__ aggIdx,
        const f4* __restrict__ aggSum, const float* __restrict__ dvals,
        float* __restrict__ out) {
    int unit = blockIdx.x * 8 + (threadIdx.x >> 5);
    int lane = threadIdx.x & 31;
    int inp = unit >> 10;
    int rem = unit & 1023;
    int n = rem >> 5;
    int tile = rem & 31;
    const float* x = (inp == 0) ? x0 : ((inp == 1) ? x1 : x2);
    int t0 = tile * TILE;

    // carry-in (exclusive prefix over preceding tiles of this row)
    f4 m = { -FLT_MAX, -FLT_MAX, -FLT_MAX, -FLT_MAX };
    i4 mi = { 0, 0, 0, 0 };
    f4 s = { 0.f, 0.f, 0.f, 0.f };
    int rowbase = (unit - tile) * (Cc / 4) + lane;
#pragma unroll 4
    for (int j = 0; j < tile; ++j) {
        int o = rowbase + j * (Cc / 4);
        f4 am = aggMax[o]; i4 ai = aggIdx[o]; f4 as = aggSum[o];
#pragma unroll
        for (int jj = 0; jj < 4; ++jj) {
            if (am[jj] > m[jj]) { m[jj] = am[jj]; mi[jj] = ai[jj]; }  // later tile must beat strictly
            s[jj] += as[jj];
        }
    }

    // MLP columns for this n (only inp==0 units write them)
    float dv = 0.f;
    if (inp == 0 && lane < 20) dv = dvals[n * 20 + lane];

    const f4* p = (const f4*)(x + ((size_t)n * Ll + t0) * Cc) + lane;
    // out row layout: inp*384 + {0:pmax, 128:pavg, 256:psum}, then 1152..1171 = d
    f4* omax = (f4*)(out + (size_t)n * Ll * OUTC + (size_t)t0 * OUTC + inp * 384) + lane;
    f4* oind = (f4*)(out + OUT_ELEMS + (size_t)inp * NLC + ((size_t)n * Ll + t0) * Cc) + lane;
    f4* oact = (f4*)(out + OUT_ELEMS + 3 * (size_t)NLC + (size_t)inp * NLC + ((size_t)n * Ll + t0) * Cc) + lane;
    float* dout = out + (size_t)n * Ll * OUTC + (size_t)t0 * OUTC + 1152 + (lane < 20 ? lane : 0);

    const float invL = 1.0f / (float)Ll;
#pragma unroll 4
    for (int tl = 0; tl < TILE; ++tl) {
        f4 v = p[(size_t)tl * (Cc / 4)];
        int t = t0 + tl;
        bool haspad = (t < Ll - 1);
        float rcnt = __builtin_amdgcn_rcpf((float)(t + 1));   // ~1 ulp, well within threshold
        f4 pmax, pidx, pavg, psum;
#pragma unroll
        for (int j = 0; j < 4; ++j) {
            s[j] += v[j];
            if (v[j] > m[j]) { m[j] = v[j]; mi[j] = t; }
            float cmax = m[j];
            pmax[j] = haspad ? fmaxf(cmax, 0.f) : cmax;
            pidx[j] = (float)((haspad && cmax < 0.f) ? (t - (Ll - 1)) : mi[j]);
            pavg[j] = s[j] * invL;
            psum[j] = s[j] * rcnt;
        }
        size_t ro = (size_t)tl * (OUTC / 4);
        nts4(&omax[ro],          pmax);
        nts4(&omax[ro + Cc / 4], pavg);   // +128 floats
        nts4(&omax[ro + Cc / 2], psum);   // +256 floats
        nts4(&oind[(size_t)tl * (Cc / 4)], pidx);
        nts4(&oact[(size_t)tl * (Cc / 4)], pmax);
        if (inp == 0 && lane < 20)
            nts1(&dout[(size_t)tl * OUTC], dv);   // coalesced 80 B row segment
    }
}

extern "C" void kernel_launch(void* const* d_in, const int* in_sizes, int n_in,
                              void* d_out, int out_size, void* d_ws, size_t ws_size,
                              hipStream_t stream) {
    const float* x0  = (const float*)d_in[0];
    const float* x1  = (const float*)d_in[1];
    const float* x2  = (const float*)d_in[2];
    const float* dem = (const float*)d_in[3];
    const float* W1  = (const float*)d_in[4];
    const float* b1  = (const float*)d_in[5];
    const float* W2  = (const float*)d_in[6];
    const float* b2  = (const float*)d_in[7];
    float* out = (float*)d_out;

    char* ws = (char*)d_ws;
    float* aggMax = (float*)ws;
    int*   aggIdx = (int*)(ws + (size_t)AGG * 4);
    float* aggSum = (float*)(ws + 2 * (size_t)AGG * 4);
    float* dvals  = (float*)(ws + 3 * (size_t)AGG * 4);

    k_agg<<<dim3(NUNITS / 8 + 1), dim3(256), 0, stream>>>(x0, x1, x2,
        (f4*)aggMax, (i4*)aggIdx, (f4*)aggSum, dem, W1, b1, W2, b2, dvals);
    k_apply<<<dim3(NUNITS / 8), dim3(256), 0, stream>>>(x0, x1, x2,
        (const f4*)aggMax, (const i4*)aggIdx, (const f4*)aggSum, dvals, out);
}